// Round 5
// baseline (274.826 us; speedup 1.0000x reference)
//
#include <hip/hip_runtime.h>
#include <hip/hip_bf16.h>

// Problem: B=2,S=2048,D=1024,E=14,F=2048; N=4096 tokens.
// ws layout (ints): [0..16) cnt, [16..32) cursor, [32..48) offs, [48) ntiles,
// [64..160) tiles (e,m0)*45, [160..4256) assign, [4256..8352) wgt(f32),
// [8352..12576) list (4224).
// hid bf16 at byte 65536 (16.78 MB); h16 bf16 at byte 65536+16777216 (8.39 MB).

#define NTOK 4096
#define NEXP 14
#define DDIM 1024
#define FDIM 2048

typedef __attribute__((ext_vector_type(8))) short short8;
typedef __attribute__((ext_vector_type(4))) float floatx4;

__device__ __forceinline__ unsigned bfr(float f) {  // f32 -> bf16 bits, RNE
  unsigned u = __float_as_uint(f);
  return (u + 0x7FFFu + ((u >> 16) & 1u)) >> 16;
}

__device__ __forceinline__ void gload16(const void* g, void* l) {
  __builtin_amdgcn_global_load_lds((const __attribute__((address_space(1))) void*)g,
                                   (__attribute__((address_space(3))) void*)l, 16, 0, 0);
}

__global__ void k_init(int* wsI, int* list) {
  int i = blockIdx.x * 256 + threadIdx.x;
  if (i < 160) wsI[i] = 0;
  if (i < 4224) list[i] = 0;
}

// one wave per token: fp64 logits -> argmax + softmax weight + expert count.
// Also emits h16 = bf16(h) for the MFMA A-path.
__global__ void k_router(const float* __restrict__ x, const float* __restrict__ rw,
                         int* __restrict__ assign, float* __restrict__ wgt,
                         int* __restrict__ cnt, unsigned short* __restrict__ h16) {
  int wid = threadIdx.x >> 6, lane = threadIdx.x & 63;
  int n = blockIdx.x * 4 + wid;
  const float* xr = x + (size_t)n * DDIM;
  unsigned short* hr = h16 + (size_t)n * DDIM;
  double acc[NEXP];
#pragma unroll
  for (int e = 0; e < NEXP; e++) acc[e] = 0.0;
  for (int d = lane; d < DDIM; d += 64) {
    float xv = xr[d];
    hr[d] = (unsigned short)bfr(xv);
    const float* rp = rw + (size_t)d * NEXP;
#pragma unroll
    for (int e = 0; e < NEXP; e++) acc[e] += (double)xv * (double)rp[e];
  }
#pragma unroll
  for (int e = 0; e < NEXP; e++)
    for (int m = 32; m > 0; m >>= 1) acc[e] += __shfl_xor(acc[e], m, 64);
  if (lane == 0) {
    int best = 0; double bv = acc[0];
    for (int e = 1; e < NEXP; e++) if (acc[e] > bv) { bv = acc[e]; best = e; }
    double s = 0.0;
    for (int e = 0; e < NEXP; e++) s += exp(acc[e] - bv);
    assign[n] = best;
    wgt[n] = (float)(1.0 / s);
    atomicAdd(&cnt[best], 1);
  }
}

__global__ void k_tiles(const int* __restrict__ cnt, int* __restrict__ offs,
                        int* __restrict__ tiles, int* __restrict__ ntl) {
  if (threadIdx.x == 0) {
    int off = 0, t = 0;
    for (int e = 0; e < NEXP; e++) { offs[e] = off; off += cnt[e]; }
    offs[NEXP] = off;
    for (int e = 0; e < NEXP; e++)
      for (int m0 = 0; m0 < cnt[e]; m0 += 128) { tiles[2 * t] = e; tiles[2 * t + 1] = m0; t++; }
    *ntl = t;
  }
}

__global__ void k_scatter(const int* __restrict__ assign, int* __restrict__ cursor,
                          const int* __restrict__ offs, int* __restrict__ list) {
  int n = blockIdx.x * 256 + threadIdx.x;
  if (n >= NTOK) return;
  int e = assign[n];
  int p = atomicAdd(&cursor[e], 1);
  list[offs[e] + p] = n;
}

// Grouped GEMM, tile 128x64, BK=64, 4 waves (2x2, each 64x32 = 4x2 frags).
// A (bf16 rows, gathered): global_load_lds direct-to-LDS, pre-swizzled per-lane
//   source addresses (linear LDS dest), zero staging registers.
// B (f32 weights): reg-staged transpose+convert (16 floats/thread), 1-deep prefetch.
// Double-buffered LDS, 2 raw barriers/iter, NO vmcnt drain: gloadA(it) is issued
// before B-reg loads(it), so WRITE_B's register wait retires A via vmcnt FIFO.
// LAYER 1: A=h16,  B=w1[e], epilogue exact-GELU -> hid (bf16)
// LAYER 2: A=hid,  B=w2[e], epilogue (+b2)*wgt  -> out (f32)
template <int LAYER>
__global__ __launch_bounds__(256, 3) void k_gemm(
    const unsigned short* __restrict__ Xb, const float* __restrict__ W,
    const float* __restrict__ Bias, const float* __restrict__ wgt,
    unsigned short* __restrict__ outB, float* __restrict__ outF,
    const int* __restrict__ wsI) {
  constexpr int K = (LAYER == 1) ? DDIM : FDIM;
  constexpr int N = (LAYER == 1) ? FDIM : DDIM;
  constexpr int NIT = K / 64;

  const int* cnt = wsI;
  const int* offs = wsI + 32;
  const int* ntl = wsI + 48;
  const int* tiles = wsI + 64;
  const int* list = wsI + 8352;

  int tI = blockIdx.x;
  if (tI >= *ntl) return;
  int e = tiles[2 * tI], m0 = tiles[2 * tI + 1];
  int rows = cnt[e] - m0;
  int base = offs[e] + m0;
  int n0 = blockIdx.y * 64;

  __shared__ char sA[2][16384];  // bf16 [128 rows][64 k], XOR-swizzled via source
  __shared__ char sB[2][8192];   // bf16 [64 cols][64 k], XOR-swizzled
  __shared__ int tokL[128];
  __shared__ float wgtL[128];

  int tid = threadIdx.x;
  if (tid < 128) {
    int tok = list[base + tid];  // pad slots zero-init -> token 0 (valid data)
    tokL[tid] = tok;
    if (LAYER == 2) wgtL[tid] = wgt[tok];
  }
  __syncthreads();

  int lane = tid & 63, wid = tid >> 6, wm = wid >> 1, wn = wid & 1;

  // A: per-lane pre-swizzled global source. Wave chunk c=wid*4+j covers rows
  // c*8..c*8+8; lane writes LDS row*128+(lane&7)*16, sources global byte
  // ((lane&7)*16) ^ ((row&7)<<4); row&7 == lane>>3.
  const char* gA[4];
  {
    unsigned sw = (unsigned)(((lane & 7) * 16) ^ ((lane >> 3) << 4));
#pragma unroll
    for (int j = 0; j < 4; j++) {
      int row = wid * 32 + j * 8 + (lane >> 3);
      gA[j] = (const char*)(Xb + (size_t)tokL[row] * K) + sw;
    }
  }

  // B: thread covers col nn = tid&63, k rows (tid>>6)*4 + j*16 + r
  int nn = tid & 63;
  int krow0 = (tid >> 6) * 4;
  const float* Wrow = W + (size_t)e * K * N + (size_t)krow0 * N + n0 + nn;

  floatx4 acc[4][2];
#pragma unroll
  for (int i = 0; i < 4; i++)
#pragma unroll
    for (int j = 0; j < 2; j++) acc[i][j] = (floatx4){0.f, 0.f, 0.f, 0.f};

  float rB[4][4];

#define ISSUE_B(k0)                                                \
  _Pragma("unroll") for (int j = 0; j < 4; j++)                    \
  _Pragma("unroll") for (int r = 0; r < 4; r++)                    \
      rB[j][r] = Wrow[(size_t)((k0) + j * 16 + r) * N];

#define WRITE_B(p)                                                                       \
  _Pragma("unroll") for (int j = 0; j < 4; j++) {                                        \
    uint2 wv;                                                                            \
    wv.x = bfr(rB[j][0]) | (bfr(rB[j][1]) << 16);                                        \
    wv.y = bfr(rB[j][2]) | (bfr(rB[j][3]) << 16);                                        \
    *(uint2*)(sB[p] + nn * 128 + (((krow0 + j * 16) * 2) ^ ((nn & 7) << 4))) = wv;       \
  }

#define GLOADA(k0, p)                                              \
  _Pragma("unroll") for (int j = 0; j < 4; j++)                    \
      gload16(gA[j] + (size_t)(k0) * 2, sA[p] + (wid * 4 + j) * 1024);

  GLOADA(0, 0);   // A before B: vmcnt FIFO invariant
  ISSUE_B(0);

  for (int it = 0; it < NIT; ++it) {
    int p = it & 1;
    __builtin_amdgcn_s_barrier();  // all reads of buf[p^1] (prev MFMA) done
    WRITE_B(p);                    // implicit vmcnt wait: retires gloadA(it) too
    __builtin_amdgcn_sched_barrier(0);
    if (it + 1 < NIT) {
      GLOADA((it + 1) * 64, p ^ 1);
      __builtin_amdgcn_sched_barrier(0);
      ISSUE_B((it + 1) * 64);
    }
    __builtin_amdgcn_sched_barrier(0);
    asm volatile("s_waitcnt lgkmcnt(0)" ::: "memory");  // sB[p] ds_writes visible
    __builtin_amdgcn_s_barrier();

    const char* A_ = sA[p];
    const char* B_ = sB[p];
#pragma unroll
    for (int kc = 0; kc < 2; kc++) {
      short8 af[4], bf[2];
      int kb = kc * 64 + ((lane >> 4) << 4);
#pragma unroll
      for (int f = 0; f < 4; f++) {
        int rr = wm * 64 + f * 16 + (lane & 15);
        af[f] = *(const short8*)(A_ + rr * 128 + (kb ^ ((rr & 7) << 4)));
      }
#pragma unroll
      for (int f = 0; f < 2; f++) {
        int cc = wn * 32 + f * 16 + (lane & 15);
        bf[f] = *(const short8*)(B_ + cc * 128 + (kb ^ ((cc & 7) << 4)));
      }
#pragma unroll
      for (int fm = 0; fm < 4; fm++)
#pragma unroll
        for (int fn = 0; fn < 2; fn++)
          acc[fm][fn] = __builtin_amdgcn_mfma_f32_16x16x32_bf16(af[fm], bf[fn], acc[fm][fn], 0, 0, 0);
    }
  }

  // epilogue. C frag mapping: col = lane&15, row = (lane>>4)*4 + r
  float bv[2];
#pragma unroll
  for (int f = 0; f < 2; f++) bv[f] = Bias[(size_t)e * N + n0 + wn * 32 + f * 16 + (lane & 15)];
#pragma unroll
  for (int fm = 0; fm < 4; fm++) {
#pragma unroll
    for (int r = 0; r < 4; r++) {
      int gr = wm * 64 + fm * 16 + ((lane >> 4) << 2) + r;
      if (gr < rows) {
        int tok = tokL[gr];
#pragma unroll
        for (int fn = 0; fn < 2; fn++) {
          int col = n0 + wn * 32 + fn * 16 + (lane & 15);
          float v = acc[fm][fn][r] + bv[fn];
          if (LAYER == 1) {
            v = 0.5f * v * (1.0f + erff(v * 0.70710678118654752f));  // exact GELU
            outB[(size_t)tok * FDIM + col] = (unsigned short)bfr(v);
          } else {
            outF[(size_t)tok * DDIM + col] = v * wgtL[gr];
          }
        }
      }
    }
  }
#undef ISSUE_B
#undef WRITE_B
#undef GLOADA
}

extern "C" void kernel_launch(void* const* d_in, const int* in_sizes, int n_in,
                              void* d_out, int out_size, void* d_ws, size_t ws_size,
                              hipStream_t stream) {
  const float* h  = (const float*)d_in[0];
  const float* rw = (const float*)d_in[1];
  const float* w1 = (const float*)d_in[2];
  const float* b1 = (const float*)d_in[3];
  const float* w2 = (const float*)d_in[4];
  const float* b2 = (const float*)d_in[5];
  float* out = (float*)d_out;

  int* wsI = (int*)d_ws;
  int* assign = wsI + 160;
  float* wgt = (float*)(wsI + 4256);
  int* list = wsI + 8352;
  unsigned short* hid = (unsigned short*)((char*)d_ws + 65536);
  unsigned short* h16 = (unsigned short*)((char*)d_ws + 65536 + 16777216);

  k_init<<<17, 256, 0, stream>>>(wsI, list);
  k_router<<<NTOK / 4, 256, 0, stream>>>(h, rw, assign, wgt, wsI, h16);
  k_tiles<<<1, 64, 0, stream>>>(wsI, wsI + 32, wsI + 64, wsI + 48);
  k_scatter<<<NTOK / 256, 256, 0, stream>>>(assign, wsI + 16, wsI + 32, list);
  // max tiles = 13 + ceil(4096/128) = 45
  k_gemm<1><<<dim3(45, FDIM / 64), 256, 0, stream>>>(h16, w1, b1, nullptr, hid, nullptr, wsI);
  k_gemm<2><<<dim3(45, DDIM / 64), 256, 0, stream>>>(hid, w2, b2, wgt, nullptr, out, wsI);
}

// Round 6
// 271.582 us; speedup vs baseline: 1.0119x; 1.0119x over previous
//
#include <hip/hip_runtime.h>
#include <hip/hip_bf16.h>

// Problem: B=2,S=2048,D=1024,E=14,F=2048; N=4096 tokens.
// ws layout (ints): [0..16) cnt, [16..32) cursor, [32..48) offs, [48) ntiles,
// [64..160) tiles (e,m0)*45, [160..4256) assign, [4256..8352) wgt(f32),
// [8352..12576) list (4224).
// hid bf16 at byte 65536 (16.78 MB); h16 bf16 at byte 65536+16777216 (8.39 MB).

#define NTOK 4096
#define NEXP 14
#define DDIM 1024
#define FDIM 2048

typedef __attribute__((ext_vector_type(8))) short short8;
typedef __attribute__((ext_vector_type(4))) float floatx4;

__device__ __forceinline__ unsigned bfr(float f) {  // f32 -> bf16 bits, RNE
  unsigned u = __float_as_uint(f);
  return (u + 0x7FFFu + ((u >> 16) & 1u)) >> 16;
}

__device__ __forceinline__ void gload16(const void* g, void* l) {
  __builtin_amdgcn_global_load_lds((const __attribute__((address_space(1))) void*)g,
                                   (__attribute__((address_space(3))) void*)l, 16, 0, 0);
}

__global__ void k_init(int* wsI, int* list) {
  int i = blockIdx.x * 256 + threadIdx.x;
  if (i < 160) wsI[i] = 0;
  if (i < 4224) list[i] = 0;
}

// one wave per token: fp64 logits -> argmax + softmax weight + expert count.
// Also emits h16 = bf16(h) for the MFMA A-path.
__global__ void k_router(const float* __restrict__ x, const float* __restrict__ rw,
                         int* __restrict__ assign, float* __restrict__ wgt,
                         int* __restrict__ cnt, unsigned short* __restrict__ h16) {
  int wid = threadIdx.x >> 6, lane = threadIdx.x & 63;
  int n = blockIdx.x * 4 + wid;
  const float* xr = x + (size_t)n * DDIM;
  unsigned short* hr = h16 + (size_t)n * DDIM;
  double acc[NEXP];
#pragma unroll
  for (int e = 0; e < NEXP; e++) acc[e] = 0.0;
  for (int d = lane; d < DDIM; d += 64) {
    float xv = xr[d];
    hr[d] = (unsigned short)bfr(xv);
    const float* rp = rw + (size_t)d * NEXP;
#pragma unroll
    for (int e = 0; e < NEXP; e++) acc[e] += (double)xv * (double)rp[e];
  }
#pragma unroll
  for (int e = 0; e < NEXP; e++)
    for (int m = 32; m > 0; m >>= 1) acc[e] += __shfl_xor(acc[e], m, 64);
  if (lane == 0) {
    int best = 0; double bv = acc[0];
    for (int e = 1; e < NEXP; e++) if (acc[e] > bv) { bv = acc[e]; best = e; }
    double s = 0.0;
    for (int e = 0; e < NEXP; e++) s += exp(acc[e] - bv);
    assign[n] = best;
    wgt[n] = (float)(1.0 / s);
    atomicAdd(&cnt[best], 1);
  }
}

__global__ void k_tiles(const int* __restrict__ cnt, int* __restrict__ offs,
                        int* __restrict__ tiles, int* __restrict__ ntl) {
  if (threadIdx.x == 0) {
    int off = 0, t = 0;
    for (int e = 0; e < NEXP; e++) { offs[e] = off; off += cnt[e]; }
    offs[NEXP] = off;
    for (int e = 0; e < NEXP; e++)
      for (int m0 = 0; m0 < cnt[e]; m0 += 128) { tiles[2 * t] = e; tiles[2 * t + 1] = m0; t++; }
    *ntl = t;
  }
}

__global__ void k_scatter(const int* __restrict__ assign, int* __restrict__ cursor,
                          const int* __restrict__ offs, int* __restrict__ list) {
  int n = blockIdx.x * 256 + threadIdx.x;
  if (n >= NTOK) return;
  int e = assign[n];
  int p = atomicAdd(&cursor[e], 1);
  list[offs[e] + p] = n;
}

// Grouped GEMM, tile 128x64, BK=64, 4 waves (2x2, each 64x32 = 4x2 frags).
// A (bf16 rows, gathered): global_load_lds direct-to-LDS, pre-swizzled per-lane
//   source addresses (linear LDS dest), zero staging registers.
// B (f32 weights): reg-staged transpose+convert (16 floats/thread), 1-deep prefetch.
// Double-buffered LDS, 2 raw barriers/iter, NO vmcnt drain: gloadA(it) is issued
// before B-reg loads(it), so WRITE_B's register wait retires A via vmcnt FIFO.
// LAYER 1: A=h16,  B=w1[e], epilogue exact-GELU -> hid (bf16)
// LAYER 2: A=hid,  B=w2[e], epilogue (+b2)*wgt  -> out (f32)
template <int LAYER>
__global__ __launch_bounds__(256, 3) void k_gemm(
    const unsigned short* __restrict__ Xb, const float* __restrict__ W,
    const float* __restrict__ Bias, const float* __restrict__ wgt,
    unsigned short* __restrict__ outB, float* __restrict__ outF,
    const int* __restrict__ wsI) {
  constexpr int K = (LAYER == 1) ? DDIM : FDIM;
  constexpr int N = (LAYER == 1) ? FDIM : DDIM;
  constexpr int NIT = K / 64;

  const int* cnt = wsI;
  const int* offs = wsI + 32;
  const int* ntl = wsI + 48;
  const int* tiles = wsI + 64;
  const int* list = wsI + 8352;

  int tI = blockIdx.x;
  if (tI >= *ntl) return;
  int e = tiles[2 * tI], m0 = tiles[2 * tI + 1];
  int rows = cnt[e] - m0;
  int base = offs[e] + m0;
  int n0 = blockIdx.y * 64;

  __shared__ char sA[2][16384];  // bf16 [128 rows][64 k], XOR-swizzled via source
  __shared__ char sB[2][8192];   // bf16 [64 cols][64 k], XOR-swizzled
  __shared__ int tokL[128];
  __shared__ float wgtL[128];

  int tid = threadIdx.x;
  if (tid < 128) {
    int tok = list[base + tid];  // pad slots zero-init -> token 0 (valid data)
    tokL[tid] = tok;
    if (LAYER == 2) wgtL[tid] = wgt[tok];
  }
  __syncthreads();

  int lane = tid & 63, wid = tid >> 6, wm = wid >> 1, wn = wid & 1;

  // A: per-lane pre-swizzled global source. Wave chunk c=wid*4+j covers rows
  // c*8..c*8+8; lane writes LDS row*128+(lane&7)*16, sources global byte
  // ((lane&7)*16) ^ ((row&7)<<4); row&7 == lane>>3.
  const char* gA[4];
  {
    unsigned sw = (unsigned)(((lane & 7) * 16) ^ ((lane >> 3) << 4));
#pragma unroll
    for (int j = 0; j < 4; j++) {
      int row = wid * 32 + j * 8 + (lane >> 3);
      gA[j] = (const char*)(Xb + (size_t)tokL[row] * K) + sw;
    }
  }

  // B: thread covers col nn = tid&63, k rows (tid>>6)*4 + j*16 + r
  int nn = tid & 63;
  int krow0 = (tid >> 6) * 4;
  const float* Wrow = W + (size_t)e * K * N + (size_t)krow0 * N + n0 + nn;

  floatx4 acc[4][2];
#pragma unroll
  for (int i = 0; i < 4; i++)
#pragma unroll
    for (int j = 0; j < 2; j++) acc[i][j] = (floatx4){0.f, 0.f, 0.f, 0.f};

  float rB[4][4];

#define ISSUE_B(k0)                                                \
  _Pragma("unroll") for (int j = 0; j < 4; j++)                    \
  _Pragma("unroll") for (int r = 0; r < 4; r++)                    \
      rB[j][r] = Wrow[(size_t)((k0) + j * 16 + r) * N];

#define WRITE_B(p)                                                                       \
  _Pragma("unroll") for (int j = 0; j < 4; j++) {                                        \
    uint2 wv;                                                                            \
    wv.x = bfr(rB[j][0]) | (bfr(rB[j][1]) << 16);                                        \
    wv.y = bfr(rB[j][2]) | (bfr(rB[j][3]) << 16);                                        \
    *(uint2*)(sB[p] + nn * 128 + (((krow0 + j * 16) * 2) ^ ((nn & 7) << 4))) = wv;       \
  }

#define GLOADA(k0, p)                                              \
  _Pragma("unroll") for (int j = 0; j < 4; j++)                    \
      gload16(gA[j] + (size_t)(k0) * 2, sA[p] + (wid * 4 + j) * 1024);

  GLOADA(0, 0);   // A before B: vmcnt FIFO invariant
  ISSUE_B(0);

  for (int it = 0; it < NIT; ++it) {
    int p = it & 1;
    __builtin_amdgcn_s_barrier();  // all reads of buf[p^1] (prev MFMA) done
    WRITE_B(p);                    // implicit vmcnt wait: retires gloadA(it) too
    __builtin_amdgcn_sched_barrier(0);
    if (it + 1 < NIT) {
      GLOADA((it + 1) * 64, p ^ 1);
      __builtin_amdgcn_sched_barrier(0);
      ISSUE_B((it + 1) * 64);
    }
    __builtin_amdgcn_sched_barrier(0);
    asm volatile("s_waitcnt lgkmcnt(0)" ::: "memory");  // sB[p] ds_writes visible
    __builtin_amdgcn_s_barrier();

    const char* A_ = sA[p];
    const char* B_ = sB[p];
#pragma unroll
    for (int kc = 0; kc < 2; kc++) {
      short8 af[4], bf[2];
      int kb = kc * 64 + ((lane >> 4) << 4);
#pragma unroll
      for (int f = 0; f < 4; f++) {
        int rr = wm * 64 + f * 16 + (lane & 15);
        af[f] = *(const short8*)(A_ + rr * 128 + (kb ^ ((rr & 7) << 4)));
      }
#pragma unroll
      for (int f = 0; f < 2; f++) {
        int cc = wn * 32 + f * 16 + (lane & 15);
        bf[f] = *(const short8*)(B_ + cc * 128 + (kb ^ ((cc & 7) << 4)));
      }
#pragma unroll
      for (int fm = 0; fm < 4; fm++)
#pragma unroll
        for (int fn = 0; fn < 2; fn++)
          acc[fm][fn] = __builtin_amdgcn_mfma_f32_16x16x32_bf16(af[fm], bf[fn], acc[fm][fn], 0, 0, 0);
    }
  }

  // epilogue. C frag mapping: col = lane&15, row = (lane>>4)*4 + r
  float bv[2];
#pragma unroll
  for (int f = 0; f < 2; f++) bv[f] = Bias[(size_t)e * N + n0 + wn * 32 + f * 16 + (lane & 15)];
#pragma unroll
  for (int fm = 0; fm < 4; fm++) {
#pragma unroll
    for (int r = 0; r < 4; r++) {
      int gr = wm * 64 + fm * 16 + ((lane >> 4) << 2) + r;
      if (gr < rows) {
        int tok = tokL[gr];
#pragma unroll
        for (int fn = 0; fn < 2; fn++) {
          int col = n0 + wn * 32 + fn * 16 + (lane & 15);
          float v = acc[fm][fn][r] + bv[fn];
          if (LAYER == 1) {
            v = 0.5f * v * (1.0f + erff(v * 0.70710678118654752f));  // exact GELU
            outB[(size_t)tok * FDIM + col] = (unsigned short)bfr(v);
          } else {
            outF[(size_t)tok * DDIM + col] = v * wgtL[gr];
          }
        }
      }
    }
  }
#undef ISSUE_B
#undef WRITE_B
#undef GLOADA
}

extern "C" void kernel_launch(void* const* d_in, const int* in_sizes, int n_in,
                              void* d_out, int out_size, void* d_ws, size_t ws_size,
                              hipStream_t stream) {
  const float* h  = (const float*)d_in[0];
  const float* rw = (const float*)d_in[1];
  const float* w1 = (const float*)d_in[2];
  const float* b1 = (const float*)d_in[3];
  const float* w2 = (const float*)d_in[4];
  const float* b2 = (const float*)d_in[5];
  float* out = (float*)d_out;

  int* wsI = (int*)d_ws;
  int* assign = wsI + 160;
  float* wgt = (float*)(wsI + 4256);
  int* list = wsI + 8352;
  unsigned short* hid = (unsigned short*)((char*)d_ws + 65536);
  unsigned short* h16 = (unsigned short*)((char*)d_ws + 65536 + 16777216);

  k_init<<<17, 256, 0, stream>>>(wsI, list);
  k_router<<<NTOK / 4, 256, 0, stream>>>(h, rw, assign, wgt, wsI, h16);
  k_tiles<<<1, 64, 0, stream>>>(wsI, wsI + 32, wsI + 64, wsI + 48);
  k_scatter<<<NTOK / 256, 256, 0, stream>>>(assign, wsI + 16, wsI + 32, list);
  // max tiles = 13 + ceil(4096/128) = 45
  k_gemm<1><<<dim3(45, FDIM / 64), 256, 0, stream>>>(h16, w1, b1, nullptr, hid, nullptr, wsI);
  k_gemm<2><<<dim3(45, DDIM / 64), 256, 0, stream>>>(hid, w2, b2, wgt, nullptr, out, wsI);
}

// Round 7
// 213.882 us; speedup vs baseline: 1.2849x; 1.2698x over previous
//
#include <hip/hip_runtime.h>
#include <hip/hip_bf16.h>

// Problem: B=2,S=2048,D=1024,E=14,F=2048; N=4096 tokens.
// ws layout (ints): [0..16) cnt, [16..32) cursor, [32..48) offs, [48) ntiles,
// [64..160) tiles (e,m0)*45, [160..4256) assign, [4256..8352) wgt(f32),
// [8352..12576) list (4224).
// hid bf16 at byte 65536 (16.78 MB); h16 bf16 at byte 65536+16777216 (8.39 MB).

#define NTOK 4096
#define NEXP 14
#define DDIM 1024
#define FDIM 2048

typedef __attribute__((ext_vector_type(8))) short short8;
typedef __attribute__((ext_vector_type(4))) float floatx4;

__device__ __forceinline__ unsigned bfr(float f) {  // f32 -> bf16 bits, RNE
  unsigned u = __float_as_uint(f);
  return (u + 0x7FFFu + ((u >> 16) & 1u)) >> 16;
}

__device__ __forceinline__ void gload16(const void* g, void* l) {
  __builtin_amdgcn_global_load_lds((const __attribute__((address_space(1))) void*)g,
                                   (__attribute__((address_space(3))) void*)l, 16, 0, 0);
}

__global__ void k_init(int* wsI, int* list) {
  int i = blockIdx.x * 256 + threadIdx.x;
  if (i < 160) wsI[i] = 0;
  if (i < 4224) list[i] = 0;
}

// one wave per token: fp64 logits -> argmax + softmax weight + expert count.
// router_w staged in LDS (coalesced float4 once per block). Also emits h16.
__global__ __launch_bounds__(256) void k_router(
    const float* __restrict__ x, const float* __restrict__ rw,
    int* __restrict__ assign, float* __restrict__ wgt,
    int* __restrict__ cnt, unsigned short* __restrict__ h16) {
  __shared__ float rwL[DDIM * NEXP];  // 57344 B
  int tid = threadIdx.x;
  for (int i = tid; i < DDIM * NEXP / 4; i += 256)
    ((float4*)rwL)[i] = ((const float4*)rw)[i];
  __syncthreads();
  int wid = tid >> 6, lane = tid & 63;
  int n = blockIdx.x * 4 + wid;
  const float* xr = x + (size_t)n * DDIM;
  unsigned short* hr = h16 + (size_t)n * DDIM;
  double acc[NEXP];
#pragma unroll
  for (int e = 0; e < NEXP; e++) acc[e] = 0.0;
  for (int d = lane; d < DDIM; d += 64) {
    float xv = xr[d];
    hr[d] = (unsigned short)bfr(xv);
    const float* rp = rwL + d * NEXP;
#pragma unroll
    for (int e = 0; e < NEXP; e++) acc[e] += (double)xv * (double)rp[e];
  }
#pragma unroll
  for (int e = 0; e < NEXP; e++)
    for (int m = 32; m > 0; m >>= 1) acc[e] += __shfl_xor(acc[e], m, 64);
  if (lane == 0) {
    int best = 0; double bv = acc[0];
    for (int e = 1; e < NEXP; e++) if (acc[e] > bv) { bv = acc[e]; best = e; }
    double s = 0.0;
    for (int e = 0; e < NEXP; e++) s += exp(acc[e] - bv);
    assign[n] = best;
    wgt[n] = (float)(1.0 / s);
    atomicAdd(&cnt[best], 1);
  }
}

// one wave: shfl-scan prefix sums + parallel tile-descriptor build
__global__ void k_tiles(const int* __restrict__ cnt, int* __restrict__ offs,
                        int* __restrict__ tiles, int* __restrict__ ntl) {
  int l = threadIdx.x;  // 0..63
  int c = (l < NEXP) ? cnt[l] : 0;
  int nt = (c + 127) >> 7;
  int sc = c, st = nt;  // inclusive scans
  for (int m = 1; m < 64; m <<= 1) {
    int t1 = __shfl_up(sc, m, 64);
    int t2 = __shfl_up(st, m, 64);
    if (l >= m) { sc += t1; st += t2; }
  }
  if (l < NEXP) offs[l] = sc - c;      // exclusive
  if (l == NEXP - 1) offs[NEXP] = sc;  // total tokens
  int totT = __shfl(st, NEXP - 1, 64);
  if (l == 0) *ntl = totT;
  __shared__ int tstart[NEXP + 1];
  if (l < NEXP) tstart[l] = st - nt;  // exclusive
  if (l == NEXP - 1) tstart[NEXP] = st;
  __syncthreads();
  if (l < totT) {
    int e = 0;
    while (tstart[e + 1] <= l) e++;
    tiles[2 * l] = e;
    tiles[2 * l + 1] = (l - tstart[e]) * 128;
  }
}

__global__ void k_scatter(const int* __restrict__ assign, int* __restrict__ cursor,
                          const int* __restrict__ offs, int* __restrict__ list) {
  int n = blockIdx.x * 256 + threadIdx.x;
  if (n >= NTOK) return;
  int e = assign[n];
  int p = atomicAdd(&cursor[e], 1);
  list[offs[e] + p] = n;
}

// Grouped GEMM, tile 128x64, BK=64, 4 waves (2x2, each 64x32 = 4x2 frags).
// A: bf16 gathered rows via global_load_lds (pre-swizzled source, linear dest).
// B: f32 weights, reg-staged convert+transpose, 2-DEEP prefetch with counted
//    vmcnt (T4): steady-state waits vmcnt(20)[auto] / vmcnt(36)[explicit],
//    never draining the FIFO; peeled tail uses 20/0.
// Grid: x = n-block, y = tile  ->  same-(e,n0) m-tiles differ by gridX*k,
//    gridX % 8 == 0 -> same XCD -> B panel re-reads hit local L2.
// LAYER 1: A=h16, B=w1[e], exact-GELU -> hid (bf16)
// LAYER 2: A=hid, B=w2[e], (+b2)*wgt  -> out (f32)
template <int LAYER>
__global__ __launch_bounds__(256, 3) void k_gemm(
    const unsigned short* __restrict__ Xb, const float* __restrict__ W,
    const float* __restrict__ Bias, const float* __restrict__ wgt,
    unsigned short* __restrict__ outB, float* __restrict__ outF,
    const int* __restrict__ wsI) {
  constexpr int K = (LAYER == 1) ? DDIM : FDIM;
  constexpr int N = (LAYER == 1) ? FDIM : DDIM;
  constexpr int NIT = K / 64;

  const int* cnt = wsI;
  const int* offs = wsI + 32;
  const int* ntl = wsI + 48;
  const int* tiles = wsI + 64;
  const int* list = wsI + 8352;

  int tI = blockIdx.y;
  if (tI >= *ntl) return;
  int e = tiles[2 * tI], m0 = tiles[2 * tI + 1];
  int rows = cnt[e] - m0;
  int base = offs[e] + m0;
  int n0 = blockIdx.x * 64;

  __shared__ char sA[2][16384];  // bf16 [128 rows][64 k], XOR-swizzled via source
  __shared__ char sB[2][8192];   // bf16 [64 cols][64 k], XOR-swizzled
  __shared__ int tokL[128];
  __shared__ float wgtL[128];

  int tid = threadIdx.x;
  if (tid < 128) {
    int tok = list[base + tid];  // pad slots zero-init -> token 0 (valid data)
    tokL[tid] = tok;
    if (LAYER == 2) wgtL[tid] = wgt[tok];
  }
  __syncthreads();

  int lane = tid & 63, wid = tid >> 6, wm = wid >> 1, wn = wid & 1;

  // A: per-lane pre-swizzled global source; LDS dest linear lane*16.
  const char* gA[4];
  {
    unsigned sw = (unsigned)(((lane & 7) * 16) ^ ((lane >> 3) << 4));
#pragma unroll
    for (int j = 0; j < 4; j++) {
      int row = wid * 32 + j * 8 + (lane >> 3);
      gA[j] = (const char*)(Xb + (size_t)tokL[row] * K) + sw;
    }
  }

  // B: thread covers col nn = tid&63, k rows krow0 + j*16 + r
  int nn = tid & 63;
  int krow0 = (tid >> 6) * 4;
  const float* Wrow0 = W + (size_t)e * K * N + (size_t)krow0 * N + n0 + nn;
  const float* Wrow1 = Wrow0 + (size_t)64 * N;

  floatx4 acc[4][2];
#pragma unroll
  for (int i = 0; i < 4; i++)
#pragma unroll
    for (int j = 0; j < 2; j++) acc[i][j] = (floatx4){0.f, 0.f, 0.f, 0.f};

  float rB0[4][4], rB1[4][4];  // static slot names (runtime-indexed -> scratch)

#define ISSUE_B(PW)                                            \
  do {                                                         \
    _Pragma("unroll") for (int j = 0; j < 4; j++)              \
    _Pragma("unroll") for (int r = 0; r < 4; r++)              \
        rB##PW[j][r] = Wrow##PW[(size_t)(j * 16 + r) * N];     \
    Wrow##PW += (size_t)128 * N;                               \
  } while (0)

#define WRITE_B(PW)                                                                    \
  _Pragma("unroll") for (int j = 0; j < 4; j++) {                                      \
    uint2 wv;                                                                          \
    wv.x = bfr(rB##PW[j][0]) | (bfr(rB##PW[j][1]) << 16);                              \
    wv.y = bfr(rB##PW[j][2]) | (bfr(rB##PW[j][3]) << 16);                              \
    *(uint2*)(sB[PW] + nn * 128 + (((krow0 + j * 16) * 2) ^ ((nn & 7) << 4))) = wv;    \
  }

#define GLOADA(k0, p)                                          \
  _Pragma("unroll") for (int j = 0; j < 4; j++)                \
      gload16(gA[j] + (size_t)(k0) * 2, sA[p] + (wid * 4 + j) * 1024);

#define MFMA_PHASE(P)                                                                    \
  do {                                                                                   \
    const char* A_ = sA[P];                                                              \
    const char* B_ = sB[P];                                                              \
    _Pragma("unroll") for (int kc = 0; kc < 2; kc++) {                                   \
      short8 af[4], bf[2];                                                               \
      int kb = kc * 64 + ((lane >> 4) << 4);                                             \
      _Pragma("unroll") for (int f = 0; f < 4; f++) {                                    \
        int rr = wm * 64 + f * 16 + (lane & 15);                                         \
        af[f] = *(const short8*)(A_ + rr * 128 + (kb ^ ((rr & 7) << 4)));                \
      }                                                                                  \
      _Pragma("unroll") for (int f = 0; f < 2; f++) {                                    \
        int cc = wn * 32 + f * 16 + (lane & 15);                                         \
        bf[f] = *(const short8*)(B_ + cc * 128 + (kb ^ ((cc & 7) << 4)));                \
      }                                                                                  \
      _Pragma("unroll") for (int fm = 0; fm < 4; fm++)                                   \
      _Pragma("unroll") for (int fn = 0; fn < 2; fn++)                                   \
          acc[fm][fn] =                                                                  \
              __builtin_amdgcn_mfma_f32_16x16x32_bf16(af[fm], bf[fn], acc[fm][fn], 0, 0, 0); \
    }                                                                                    \
  } while (0)

  // STEP: issue order per iter keeps vmcnt FIFO counts exact:
  //   WRITE_B(P)  -> compiler-auto wait vmcnt(20)  [A(it)4 + B(it+1)16 newer]
  //   GLOADA(it+1), ISSUE_B(it+2)  -> outstanding 40
  //   explicit vmcnt(VM=36) retires A(it); lgkmcnt(0) flushes ds_writes
#define STEP(P, DO1, DO2, K1, VM)                                     \
  do {                                                                \
    __builtin_amdgcn_s_barrier();                                     \
    WRITE_B(P);                                                       \
    __builtin_amdgcn_sched_barrier(0);                                \
    if (DO1) { GLOADA((K1), P ^ 1); }                                 \
    if (DO2) { ISSUE_B(P); }                                          \
    __builtin_amdgcn_sched_barrier(0);                                \
    asm volatile("s_waitcnt vmcnt(" #VM ") lgkmcnt(0)" ::: "memory"); \
    __builtin_amdgcn_sched_barrier(0);                                \
    __builtin_amdgcn_s_barrier();                                     \
    MFMA_PHASE(P);                                                    \
  } while (0)

  // prologue: B(0), A(0), B(1) -- order matters for the counts above
  ISSUE_B(0);
  GLOADA(0, 0);
  ISSUE_B(1);

  for (int it = 0; it < NIT - 2; it += 2) {
    STEP(0, 1, 1, (it + 1) * 64, 36);
    STEP(1, 1, 1, (it + 2) * 64, 36);
  }
  STEP(0, 1, 0, (NIT - 1) * 64, 20);  // issues A(NIT-1) only
  STEP(1, 0, 0, 0, 0);                // final drain

#undef ISSUE_B
#undef WRITE_B
#undef GLOADA
#undef MFMA_PHASE
#undef STEP

  // epilogue. C frag mapping: col = lane&15, row = (lane>>4)*4 + r
  float bv[2];
#pragma unroll
  for (int f = 0; f < 2; f++) bv[f] = Bias[(size_t)e * N + n0 + wn * 32 + f * 16 + (lane & 15)];
#pragma unroll
  for (int fm = 0; fm < 4; fm++) {
#pragma unroll
    for (int r = 0; r < 4; r++) {
      int gr = wm * 64 + fm * 16 + ((lane >> 4) << 2) + r;
      if (gr < rows) {
        int tok = tokL[gr];
#pragma unroll
        for (int fn = 0; fn < 2; fn++) {
          int col = n0 + wn * 32 + fn * 16 + (lane & 15);
          float v = acc[fm][fn][r] + bv[fn];
          if (LAYER == 1) {
            v = 0.5f * v * (1.0f + erff(v * 0.70710678118654752f));  // exact GELU
            outB[(size_t)tok * FDIM + col] = (unsigned short)bfr(v);
          } else {
            outF[(size_t)tok * DDIM + col] = v * wgtL[gr];
          }
        }
      }
    }
  }
}

extern "C" void kernel_launch(void* const* d_in, const int* in_sizes, int n_in,
                              void* d_out, int out_size, void* d_ws, size_t ws_size,
                              hipStream_t stream) {
  const float* h  = (const float*)d_in[0];
  const float* rw = (const float*)d_in[1];
  const float* w1 = (const float*)d_in[2];
  const float* b1 = (const float*)d_in[3];
  const float* w2 = (const float*)d_in[4];
  const float* b2 = (const float*)d_in[5];
  float* out = (float*)d_out;

  int* wsI = (int*)d_ws;
  int* assign = wsI + 160;
  float* wgt = (float*)(wsI + 4256);
  int* list = wsI + 8352;
  unsigned short* hid = (unsigned short*)((char*)d_ws + 65536);
  unsigned short* h16 = (unsigned short*)((char*)d_ws + 65536 + 16777216);

  k_init<<<17, 256, 0, stream>>>(wsI, list);
  k_router<<<NTOK / 4, 256, 0, stream>>>(h, rw, assign, wgt, wsI, h16);
  k_tiles<<<1, 64, 0, stream>>>(wsI, wsI + 32, wsI + 64, wsI + 48);
  k_scatter<<<NTOK / 256, 256, 0, stream>>>(assign, wsI + 16, wsI + 32, list);
  // max tiles = 13 + ceil(4096/128) = 45; grid x = n-blocks (mult of 8 -> XCD-local m-tiles)
  k_gemm<1><<<dim3(FDIM / 64, 45), 256, 0, stream>>>(h16, w1, b1, nullptr, hid, nullptr, wsI);
  k_gemm<2><<<dim3(DDIM / 64, 45), 256, 0, stream>>>(hid, w2, b2, wgt, nullptr, out, wsI);
}